// Round 10
// baseline (148.110 us; speedup 1.0000x reference)
//
#include <hip/hip_runtime.h>
#include <hip/hip_bf16.h>
#include <stdint.h>

#define T_DIM 2048
#define C_DIM 1024
#define H_DIM 16
#define D_HEAD 64
#define N_QKV 3072
#define CQ 0.18033688011112042f   // log2(e)/8

typedef __bf16 bf16;
typedef __bf16 bf16x8 __attribute__((ext_vector_type(8)));
typedef __bf16 bf16x4 __attribute__((ext_vector_type(4)));
typedef __bf16 bf16x2 __attribute__((ext_vector_type(2)));
typedef float f32x4 __attribute__((ext_vector_type(4)));
typedef short s16x4 __attribute__((ext_vector_type(4)));

__device__ __forceinline__ void lds_load16(const void* g, void* l) {
    __builtin_amdgcn_global_load_lds(
        (const __attribute__((address_space(1))) void*)g,
        (__attribute__((address_space(3))) void*)l, 16, 0, 0);
}

__device__ __forceinline__ f32x4 mfma16(bf16x4 a, bf16x4 b, f32x4 c) {
#if __has_builtin(__builtin_amdgcn_mfma_f32_16x16x16_bf16)
    return __builtin_amdgcn_mfma_f32_16x16x16_bf16(a, b, c, 0, 0, 0);
#elif __has_builtin(__builtin_amdgcn_mfma_f32_16x16x16bf16_1k)
    union { bf16x4 v; s16x4 s; } ua, ub;
    ua.v = a; ub.v = b;
    return __builtin_amdgcn_mfma_f32_16x16x16bf16_1k(ua.s, ub.s, c, 0, 0, 0);
#else
    asm volatile("v_mfma_f32_16x16x16_bf16 %0, %1, %2, %0"
                 : "+v"(c) : "v"(a), "v"(b));
    return c;
#endif
}

// ---- prep v2: blocks 0..1023 cast x; blocks 1024..1791 transpose W_qkv (64x64 tiles,
// bf16x8 coalesced stores: 128B per out-row per 4 lanes vs old 64B/8 lanes).
// W_proj transpose moved into the flash launch (overlaps flash's idle pipes).
__global__ void prep_kernel(const float* __restrict__ x, bf16* __restrict__ xb,
                            const float* __restrict__ Wq, bf16* __restrict__ WqT) {
    __shared__ float tile[64][65];
    int bid = blockIdx.x;
    int t = threadIdx.x;
    if (bid < 1024) {
        int i = (bid * 256 + t) * 8;
        float4 a = *(const float4*)(x + i);
        float4 b = *(const float4*)(x + i + 4);
        bf16x8 o;
        o[0] = (bf16)a.x; o[1] = (bf16)a.y; o[2] = (bf16)a.z; o[3] = (bf16)a.w;
        o[4] = (bf16)b.x; o[5] = (bf16)b.y; o[6] = (bf16)b.z; o[7] = (bf16)b.w;
        *(bf16x8*)(xb + i) = o;
        return;
    }
    int b2 = bid - 1024;                       // 0..767 = 48 col-tiles x 16 k-tiles
    int nb = (b2 % 48) * 64, kb = (b2 / 48) * 64;
    {
        int r = t >> 2, c16 = (t & 3) * 16;    // load: 4 lanes x 64B per row -> 256B coalesced
        const float* src = Wq + (size_t)(kb + r) * N_QKV + nb + c16;
        #pragma unroll
        for (int j = 0; j < 4; ++j) {
            float4 v = *(const float4*)(src + j * 4);
            tile[r][c16 + j * 4 + 0] = v.x; tile[r][c16 + j * 4 + 1] = v.y;
            tile[r][c16 + j * 4 + 2] = v.z; tile[r][c16 + j * 4 + 3] = v.w;
        }
    }
    __syncthreads();
    {
        int n = t >> 2, s = (t & 3) * 16;      // store: 4 lanes x 32B per out-row -> 128B
        bf16x8 o0, o1;
        #pragma unroll
        for (int j = 0; j < 8; ++j) { o0[j] = (bf16)tile[s + j][n]; o1[j] = (bf16)tile[s + 8 + j][n]; }
        bf16* dst = WqT + (size_t)(nb + n) * C_DIM + kb + s;
        *(bf16x8*)(dst)     = o0;
        *(bf16x8*)(dst + 8) = o1;
    }
}

// ---------------- QKV GEMM 128x128, BK=64, 2-phase DMA pipeline, XCD-swizzled ----------------
#define QKV_STAGE(BUF, K0) do {                                                      \
    lds_load16(ga + (K0),                            &As[BUF][0][(w * 16) * 32]);    \
    lds_load16(ga + (K0) + 32,                       &As[BUF][1][(w * 16) * 32]);    \
    lds_load16(ga + (size_t)64 * C_DIM + (K0),       &As[BUF][0][(64 + w * 16) * 32]); \
    lds_load16(ga + (size_t)64 * C_DIM + (K0) + 32,  &As[BUF][1][(64 + w * 16) * 32]); \
    lds_load16(gb + (K0),                            &Bs[BUF][0][(w * 16) * 32]);    \
    lds_load16(gb + (K0) + 32,                       &Bs[BUF][1][(w * 16) * 32]);    \
    lds_load16(gb + (size_t)64 * C_DIM + (K0),       &Bs[BUF][0][(64 + w * 16) * 32]); \
    lds_load16(gb + (size_t)64 * C_DIM + (K0) + 32,  &Bs[BUF][1][(64 + w * 16) * 32]); \
} while (0)

#define QKV_COMPUTE(BUF) do {                                                \
    _Pragma("unroll")                                                        \
    for (int p = 0; p < 2; ++p) {                                            \
        bf16x8 af[4], bfr[4];                                                \
        _Pragma("unroll")                                                    \
        for (int mi = 0; mi < 4; ++mi) af[mi]  = *(const bf16x8*)&As[BUF][p][(wm + mi * 16 + lo16) * 32 + quad * 8]; \
        _Pragma("unroll")                                                    \
        for (int ni = 0; ni < 4; ++ni) bfr[ni] = *(const bf16x8*)&Bs[BUF][p][(wn + ni * 16 + lo16) * 32 + quad * 8]; \
        _Pragma("unroll")                                                    \
        for (int mi = 0; mi < 4; ++mi)                                       \
            _Pragma("unroll")                                                \
            for (int ni = 0; ni < 4; ++ni)                                   \
                acc[mi][ni] = __builtin_amdgcn_mfma_f32_16x16x32_bf16(af[mi], bfr[ni], acc[mi][ni], 0, 0, 0); \
    }                                                                        \
} while (0)

#define WAIT_AND_BARRIER() do {                                              \
    asm volatile("s_waitcnt vmcnt(0)" ::: "memory");                         \
    __builtin_amdgcn_s_barrier();                                            \
} while (0)

__global__ __launch_bounds__(256, 2) void qkv_gemm_kernel(
    const bf16* __restrict__ A, const bf16* __restrict__ Bt,
    const float* __restrict__ bias, bf16* __restrict__ qkv)
{
    __shared__ __align__(16) bf16 As[2][2][128 * 32];
    __shared__ __align__(16) bf16 Bs[2][2][128 * 32];
    const int bid = blockIdx.x;
    const int xcd = bid & 7, slot = bid >> 3;            // slot 0..47
    const int rowBase = (slot / 3) * 128;                // 16 row-blocks
    const int colBase = (xcd * 3 + (slot % 3)) * 128;    // 24 col-blocks
    const int tid = threadIdx.x, lane = tid & 63, w = tid >> 6;
    const int lo16 = lane & 15, quad = lane >> 4;
    const int wm = (w & 1) * 64, wn = (w >> 1) * 64;

    const bf16* ga = A  + (size_t)(rowBase + w * 16 + (lane >> 2)) * C_DIM + (lane & 3) * 8;
    const bf16* gb = Bt + (size_t)(colBase + w * 16 + (lane >> 2)) * C_DIM + (lane & 3) * 8;

    f32x4 acc[4][4] = {};

    QKV_STAGE(0, 0);
    WAIT_AND_BARRIER();

    for (int k0 = 0; k0 < C_DIM; k0 += 128) {
        QKV_STAGE(1, k0 + 64);
        QKV_COMPUTE(0);
        WAIT_AND_BARRIER();
        if (k0 + 128 < C_DIM) QKV_STAGE(0, k0 + 128);
        QKV_COMPUTE(1);
        WAIT_AND_BARRIER();
    }

    const float scale = (colBase < C_DIM) ? CQ : 1.0f;   // Q region prescale (128 | 1024)
    #pragma unroll
    for (int ni = 0; ni < 4; ++ni) {
        int col = colBase + wn + ni * 16 + lo16;
        float bv = bias[col];
        #pragma unroll
        for (int mi = 0; mi < 4; ++mi) {
            int row0 = rowBase + wm + mi * 16 + quad * 4;
            #pragma unroll
            for (int r = 0; r < 4; ++r)
                qkv[(size_t)(row0 + r) * N_QKV + col] = (bf16)((acc[mi][ni][r] + bv) * scale);
        }
    }
}

// ---------------- flash attention (round-3 v10 body, best total) + W_proj transpose tail ----------------
// bid < 512: flash (unchanged from the 145.75us config). bid >= 512: 256 blocks transpose
// W_proj 64x64 tiles -- flash's pipes are ~55% idle, so this work backfills instead of
// occupying a serial prep slot (its consumer, proj_gemm, launches after flash).
__global__ __launch_bounds__(512, 2) void flash_kernel(
    const bf16* __restrict__ qkv,    // [T][3C]
    const float* __restrict__ Wp,    // [C][C] f32
    bf16* __restrict__ WpT,          // [C][C] bf16 transposed
    bf16* __restrict__ y)            // [T][C]
{
    __shared__ union {
        __align__(16) bf16 Vt[4][64][38];       // [w>>1][d][(w&1)*16 + s']
        float Ored[8][16][66];                  // [wave][d_local][q]
        float tile[64][66];                     // W_proj transpose staging
    } u;
    __shared__ float lred[8][64];

    const int bid = blockIdx.x;
    const int tid  = threadIdx.x;

    if (bid >= 512) {
        // ---- W_proj transpose: 256 tiles of 64x64, 512 threads ----
        int b2 = bid - 512;                    // 16 col-tiles x 16 k-tiles
        int nb = (b2 & 15) * 64, kb = (b2 >> 4) * 64;
        {
            int r = tid >> 3, c8 = (tid & 7) * 8;   // 8 lanes x 32B per row -> 256B coalesced
            const float* src = Wp + (size_t)(kb + r) * C_DIM + nb + c8;
            float4 a = *(const float4*)(src);
            float4 b = *(const float4*)(src + 4);
            u.tile[r][c8 + 0] = a.x; u.tile[r][c8 + 1] = a.y;
            u.tile[r][c8 + 2] = a.z; u.tile[r][c8 + 3] = a.w;
            u.tile[r][c8 + 4] = b.x; u.tile[r][c8 + 5] = b.y;
            u.tile[r][c8 + 6] = b.z; u.tile[r][c8 + 7] = b.w;
        }
        __syncthreads();
        {
            int n = tid >> 3, s = (tid & 7) * 8;    // 8 lanes x 16B per out-row -> 128B
            bf16x8 ov;
            #pragma unroll
            for (int j = 0; j < 8; ++j) ov[j] = (bf16)u.tile[s + j][n];
            *(bf16x8*)(WpT + (size_t)(nb + n) * C_DIM + kb + s) = ov;
        }
        return;
    }

    const int xcd = bid & 7, slot = bid >> 3;   // slot 0..63
    const int h = xcd * 2 + (slot & 1);
    const int qb = slot >> 1;                   // 0..31
    const int lane = tid & 63, w = tid >> 6;    // w in 0..7
    const int lo16 = lane & 15, quad = lane >> 4;

    bf16x8 qf[4][2];
    #pragma unroll
    for (int nq = 0; nq < 4; ++nq)
        #pragma unroll
        for (int dk = 0; dk < 2; ++dk)
            qf[nq][dk] = *(const bf16x8*)(qkv + (size_t)(qb * 64 + nq * 16 + lo16) * N_QKV
                                          + h * D_HEAD + dk * 32 + quad * 8);

    f32x4 o_t[4][4] = {};
    f32x4 o_l[4] = {};                          // l accumulated via MFMA ones-trick
    bf16x4 ones1;
    ones1[0] = (bf16)1.0f; ones1[1] = (bf16)1.0f; ones1[2] = (bf16)1.0f; ones1[3] = (bf16)1.0f;

    const bf16* kfb = qkv + (size_t)(w * 16 + lo16) * N_QKV + C_DIM + h * D_HEAD + quad * 8;
    const unsigned short* vb16 = (const unsigned short*)(qkv + 2 * C_DIM + h * D_HEAD);

    bf16x8 kf0 = *(const bf16x8*)(kfb);
    bf16x8 kf1 = *(const bf16x8*)(kfb + 32);
    unsigned short vreg[16];
    #pragma unroll
    for (int i = 0; i < 16; ++i)
        vreg[i] = vb16[(size_t)(w * 16 + i) * N_QKV + lane];

    bf16* vdst = &u.Vt[w >> 1][lane][(w & 1) * 16];

    for (int kt = 0; kt < T_DIM / 128; ++kt) {
        union { bf16x8 v; unsigned short us[8]; } p0, p1;
        #pragma unroll
        for (int i = 0; i < 8; ++i) { p0.us[i] = vreg[i]; p1.us[i] = vreg[8 + i]; }
        *(bf16x8*)vdst       = p0.v;
        *(bf16x8*)(vdst + 8) = p1.v;

        // early V-fragment reads: in-order DS makes these RAW-safe; latency hides
        // under prefetch issue + QK MFMA + exp2 below.
        bf16x4 vf[4];
        #pragma unroll
        for (int mi = 0; mi < 4; ++mi)
            vf[mi] = *(const bf16x4*)&u.Vt[w >> 1][mi * 16 + lo16][(w & 1) * 16 + quad * 4];

        bf16x8 nkf0 = kf0, nkf1 = kf1;
        if (kt + 1 < T_DIM / 128) {
            const bf16* kp = kfb + (size_t)(kt + 1) * 128 * N_QKV;
            nkf0 = *(const bf16x8*)(kp);
            nkf1 = *(const bf16x8*)(kp + 32);
            #pragma unroll
            for (int i = 0; i < 16; ++i)
                vreg[i] = vb16[(size_t)((kt + 1) * 128 + w * 16 + i) * N_QKV + lane];
        }

        f32x4 st[4];
        #pragma unroll
        for (int nq = 0; nq < 4; ++nq) {
            f32x4 z = {};
            z = __builtin_amdgcn_mfma_f32_16x16x32_bf16(kf0, qf[nq][0], z, 0, 0, 0);
            st[nq] = __builtin_amdgcn_mfma_f32_16x16x32_bf16(kf1, qf[nq][1], z, 0, 0, 0);
        }

        bf16x4 pb[4];
        #pragma unroll
        for (int nq = 0; nq < 4; ++nq)
            #pragma unroll
            for (int r = 0; r < 4; ++r)
                pb[nq][r] = (bf16)__builtin_amdgcn_exp2f(st[nq][r]);

        __builtin_amdgcn_s_setprio(1);
        #pragma unroll
        for (int nq = 0; nq < 4; ++nq)
            o_l[nq] = mfma16(ones1, pb[nq], o_l[nq]);
        #pragma unroll
        for (int mi = 0; mi < 4; ++mi)
            #pragma unroll
            for (int nq = 0; nq < 4; ++nq)
                o_t[mi][nq] = mfma16(vf[mi], pb[nq], o_t[mi][nq]);
        __builtin_amdgcn_s_setprio(0);

        kf0 = nkf0; kf1 = nkf1;
    }

    // o_l[nq][r] holds sum over this wave's 16 keys for q = nq*16+lo16
    #pragma unroll
    for (int nq = 0; nq < 4; ++nq)
        if (quad == 0) lred[w][nq * 16 + lo16] = o_l[nq][0];

    const int q8 = tid >> 3, dh = tid & 7;
    float linv = 0.f;
    #pragma unroll
    for (int mi = 0; mi < 4; ++mi) {
        __syncthreads();
        #pragma unroll
        for (int nq = 0; nq < 4; ++nq)
            #pragma unroll
            for (int r = 0; r < 4; ++r)
                u.Ored[w][quad * 4 + r][nq * 16 + lo16] = o_t[mi][nq][r];
        __syncthreads();
        if (mi == 0) {
            float ls = 0.f;
            #pragma unroll
            for (int j = 0; j < 8; ++j) ls += lred[j][q8];
            linv = 1.0f / ls;
        }
        bf16x2 ov;
        #pragma unroll
        for (int dj = 0; dj < 2; ++dj) {
            int d = dh * 2 + dj;
            float s = 0.f;
            #pragma unroll
            for (int j = 0; j < 8; ++j) s += u.Ored[j][d][q8];
            ov[dj] = (bf16)(s * linv);
        }
        *(bf16x2*)&y[(size_t)(qb * 64 + q8) * C_DIM + h * D_HEAD + mi * 16 + dh * 2] = ov;
    }
}

// ---------------- proj GEMM 64x64, BK=64, 2-phase DMA pipeline ----------------
#define PROJ_STAGE(BUF, K0) do {                                             \
    lds_load16(ga + (K0),      &As[BUF][0][(w * 16) * 32]);                  \
    lds_load16(ga + (K0) + 32, &As[BUF][1][(w * 16) * 32]);                  \
    lds_load16(gb + (K0),      &Bs[BUF][0][(w * 16) * 32]);                  \
    lds_load16(gb + (K0) + 32, &Bs[BUF][1][(w * 16) * 32]);                  \
} while (0)

#define PROJ_COMPUTE(BUF) do {                                               \
    _Pragma("unroll")                                                        \
    for (int p = 0; p < 2; ++p) {                                            \
        bf16x8 af[2], bfr[2];                                                \
        _Pragma("unroll")                                                    \
        for (int mi = 0; mi < 2; ++mi) af[mi]  = *(const bf16x8*)&As[BUF][p][(wm + mi * 16 + lo16) * 32 + quad * 8]; \
        _Pragma("unroll")                                                    \
        for (int ni = 0; ni < 2; ++ni) bfr[ni] = *(const bf16x8*)&Bs[BUF][p][(wn + ni * 16 + lo16) * 32 + quad * 8]; \
        _Pragma("unroll")                                                    \
        for (int mi = 0; mi < 2; ++mi)                                       \
            _Pragma("unroll")                                                \
            for (int ni = 0; ni < 2; ++ni)                                   \
                acc[mi][ni] = __builtin_amdgcn_mfma_f32_16x16x32_bf16(af[mi], bfr[ni], acc[mi][ni], 0, 0, 0); \
    }                                                                        \
} while (0)

__global__ __launch_bounds__(256, 4) void proj_gemm_kernel(
    const bf16* __restrict__ A, const bf16* __restrict__ Bt,
    const float* __restrict__ bias, float* __restrict__ out)
{
    __shared__ __align__(16) bf16 As[2][2][64 * 32];
    __shared__ __align__(16) bf16 Bs[2][2][64 * 32];
    const int bid = blockIdx.x;
    const int xcd = bid & 7, slot = bid >> 3;            // slot 0..63
    const int colBase = (xcd * 2 + (slot & 1)) * 64;
    const int rowBase = (slot >> 1) * 64;
    const int tid = threadIdx.x, lane = tid & 63, w = tid >> 6;
    const int lo16 = lane & 15, quad = lane >> 4;
    const int wm = (w & 1) * 32, wn = (w >> 1) * 32;

    const bf16* ga = A  + (size_t)(rowBase + w * 16 + (lane >> 2)) * C_DIM + (lane & 3) * 8;
    const bf16* gb = Bt + (size_t)(colBase + w * 16 + (lane >> 2)) * C_DIM + (lane & 3) * 8;

    f32x4 acc[2][2] = {};

    PROJ_STAGE(0, 0);
    WAIT_AND_BARRIER();

    for (int k0 = 0; k0 < C_DIM; k0 += 128) {
        PROJ_STAGE(1, k0 + 64);
        PROJ_COMPUTE(0);
        WAIT_AND_BARRIER();
        if (k0 + 128 < C_DIM) PROJ_STAGE(0, k0 + 128);
        PROJ_COMPUTE(1);
        WAIT_AND_BARRIER();
    }

    #pragma unroll
    for (int ni = 0; ni < 2; ++ni) {
        int col = colBase + wn + ni * 16 + lo16;
        float bv = bias[col];
        #pragma unroll
        for (int mi = 0; mi < 2; ++mi) {
            int row0 = rowBase + wm + mi * 16 + quad * 4;
            #pragma unroll
            for (int r = 0; r < 4; ++r)
                out[(size_t)(row0 + r) * C_DIM + col] = acc[mi][ni][r] + bv;
        }
    }
}

extern "C" void kernel_launch(void* const* d_in, const int* in_sizes, int n_in,
                              void* d_out, int out_size, void* d_ws, size_t ws_size,
                              hipStream_t stream) {
    const float* x      = (const float*)d_in[0];
    const float* W_qkv  = (const float*)d_in[1];
    const float* b_qkv  = (const float*)d_in[2];
    const float* W_proj = (const float*)d_in[3];
    const float* b_proj = (const float*)d_in[4];
    float* out = (float*)d_out;

    char* ws = (char*)d_ws;
    bf16* xb      = (bf16*)(ws);                 // [0,4) MB
    bf16* Wqkv_t  = (bf16*)(ws + (4  << 20));    // [4,10) MB
    bf16* Wproj_t = (bf16*)(ws + (10 << 20));    // [10,12) MB
    bf16* qkv_bf  = (bf16*)(ws + (12 << 20));    // [12,24) MB  interleaved [T][3072], Q prescaled
    bf16* yb      = (bf16*)(ws + (24 << 20));    // [24,28) MB

    prep_kernel<<<1792, 256, 0, stream>>>(x, xb, W_qkv, Wqkv_t);

    qkv_gemm_kernel<<<384, 256, 0, stream>>>(xb, Wqkv_t, b_qkv, qkv_bf);

    flash_kernel<<<768, 512, 0, stream>>>(qkv_bf, W_proj, Wproj_t, yb);

    proj_gemm_kernel<<<512, 256, 0, stream>>>(yb, Wproj_t, b_proj, out);
}

// Round 11
// 144.892 us; speedup vs baseline: 1.0222x; 1.0222x over previous
//
#include <hip/hip_runtime.h>
#include <hip/hip_bf16.h>
#include <stdint.h>

#define T_DIM 2048
#define C_DIM 1024
#define H_DIM 16
#define D_HEAD 64
#define N_QKV 3072
#define CQ 0.18033688011112042f   // log2(e)/8

typedef __bf16 bf16;
typedef __bf16 bf16x8 __attribute__((ext_vector_type(8)));
typedef __bf16 bf16x4 __attribute__((ext_vector_type(4)));
typedef __bf16 bf16x2 __attribute__((ext_vector_type(2)));
typedef float f32x4 __attribute__((ext_vector_type(4)));
typedef short s16x4 __attribute__((ext_vector_type(4)));

__device__ __forceinline__ void lds_load16(const void* g, void* l) {
    __builtin_amdgcn_global_load_lds(
        (const __attribute__((address_space(1))) void*)g,
        (__attribute__((address_space(3))) void*)l, 16, 0, 0);
}

__device__ __forceinline__ f32x4 mfma16(bf16x4 a, bf16x4 b, f32x4 c) {
#if __has_builtin(__builtin_amdgcn_mfma_f32_16x16x16_bf16)
    return __builtin_amdgcn_mfma_f32_16x16x16_bf16(a, b, c, 0, 0, 0);
#elif __has_builtin(__builtin_amdgcn_mfma_f32_16x16x16bf16_1k)
    union { bf16x4 v; s16x4 s; } ua, ub;
    ua.v = a; ub.v = b;
    return __builtin_amdgcn_mfma_f32_16x16x16bf16_1k(ua.s, ub.s, c, 0, 0, 0);
#else
    asm volatile("v_mfma_f32_16x16x16_bf16 %0, %1, %2, %0"
                 : "+v"(c) : "v"(a), "v"(b));
    return c;
#endif
}

// ---- merged prep: blocks 0..1023 cast x; blocks 1024..5119 transpose both weights ----
__global__ void prep_kernel(const float* __restrict__ x, bf16* __restrict__ xb,
                            const float* __restrict__ Wq, bf16* __restrict__ WqT,
                            const float* __restrict__ Wp, bf16* __restrict__ WpT) {
    __shared__ float tile[32][33];
    int bid = blockIdx.x;
    int t = threadIdx.x;
    if (bid < 1024) {
        int i = (bid * 256 + t) * 8;
        float4 a = *(const float4*)(x + i);
        float4 b = *(const float4*)(x + i + 4);
        bf16x8 o;
        o[0] = (bf16)a.x; o[1] = (bf16)a.y; o[2] = (bf16)a.z; o[3] = (bf16)a.w;
        o[4] = (bf16)b.x; o[5] = (bf16)b.y; o[6] = (bf16)b.z; o[7] = (bf16)b.w;
        *(bf16x8*)(xb + i) = o;
        return;
    }
    bid -= 1024;
    const float* in; bf16* out; int N, nb, kb;
    if (bid < 3072) { in = Wq; out = WqT; N = N_QKV; nb = (bid % 96) * 32; kb = (bid / 96) * 32; }
    else { bid -= 3072; in = Wp; out = WpT; N = C_DIM; nb = (bid % 32) * 32; kb = (bid / 32) * 32; }
    int r = t >> 3, c4 = (t & 7) * 4;
    float4 v = *(const float4*)(in + (size_t)(kb + r) * N + nb + c4);
    tile[r][c4 + 0] = v.x; tile[r][c4 + 1] = v.y;
    tile[r][c4 + 2] = v.z; tile[r][c4 + 3] = v.w;
    __syncthreads();
    bf16x4 ov;
    ov[0] = (bf16)tile[c4 + 0][r]; ov[1] = (bf16)tile[c4 + 1][r];
    ov[2] = (bf16)tile[c4 + 2][r]; ov[3] = (bf16)tile[c4 + 3][r];
    *(bf16x4*)(out + (size_t)(nb + r) * C_DIM + kb + c4) = ov;
}

// ---------------- QKV GEMM 128x128, BK=64, 2-phase DMA pipeline, XCD-swizzled ----------------
#define QKV_STAGE(BUF, K0) do {                                                      \
    lds_load16(ga + (K0),                            &As[BUF][0][(w * 16) * 32]);    \
    lds_load16(ga + (K0) + 32,                       &As[BUF][1][(w * 16) * 32]);    \
    lds_load16(ga + (size_t)64 * C_DIM + (K0),       &As[BUF][0][(64 + w * 16) * 32]); \
    lds_load16(ga + (size_t)64 * C_DIM + (K0) + 32,  &As[BUF][1][(64 + w * 16) * 32]); \
    lds_load16(gb + (K0),                            &Bs[BUF][0][(w * 16) * 32]);    \
    lds_load16(gb + (K0) + 32,                       &Bs[BUF][1][(w * 16) * 32]);    \
    lds_load16(gb + (size_t)64 * C_DIM + (K0),       &Bs[BUF][0][(64 + w * 16) * 32]); \
    lds_load16(gb + (size_t)64 * C_DIM + (K0) + 32,  &Bs[BUF][1][(64 + w * 16) * 32]); \
} while (0)

#define QKV_COMPUTE(BUF) do {                                                \
    _Pragma("unroll")                                                        \
    for (int p = 0; p < 2; ++p) {                                            \
        bf16x8 af[4], bfr[4];                                                \
        _Pragma("unroll")                                                    \
        for (int mi = 0; mi < 4; ++mi) af[mi]  = *(const bf16x8*)&As[BUF][p][(wm + mi * 16 + lo16) * 32 + quad * 8]; \
        _Pragma("unroll")                                                    \
        for (int ni = 0; ni < 4; ++ni) bfr[ni] = *(const bf16x8*)&Bs[BUF][p][(wn + ni * 16 + lo16) * 32 + quad * 8]; \
        _Pragma("unroll")                                                    \
        for (int mi = 0; mi < 4; ++mi)                                       \
            _Pragma("unroll")                                                \
            for (int ni = 0; ni < 4; ++ni)                                   \
                acc[mi][ni] = __builtin_amdgcn_mfma_f32_16x16x32_bf16(af[mi], bfr[ni], acc[mi][ni], 0, 0, 0); \
    }                                                                        \
} while (0)

#define WAIT_AND_BARRIER() do {                                              \
    asm volatile("s_waitcnt vmcnt(0)" ::: "memory");                         \
    __builtin_amdgcn_s_barrier();                                            \
} while (0)

__global__ __launch_bounds__(256, 2) void qkv_gemm_kernel(
    const bf16* __restrict__ A, const bf16* __restrict__ Bt,
    const float* __restrict__ bias, bf16* __restrict__ qkv)
{
    __shared__ __align__(16) bf16 As[2][2][128 * 32];
    __shared__ __align__(16) bf16 Bs[2][2][128 * 32];
    const int bid = blockIdx.x;
    const int xcd = bid & 7, slot = bid >> 3;            // slot 0..47
    const int rowBase = (slot / 3) * 128;                // 16 row-blocks
    const int colBase = (xcd * 3 + (slot % 3)) * 128;    // 24 col-blocks
    const int tid = threadIdx.x, lane = tid & 63, w = tid >> 6;
    const int lo16 = lane & 15, quad = lane >> 4;
    const int wm = (w & 1) * 64, wn = (w >> 1) * 64;

    const bf16* ga = A  + (size_t)(rowBase + w * 16 + (lane >> 2)) * C_DIM + (lane & 3) * 8;
    const bf16* gb = Bt + (size_t)(colBase + w * 16 + (lane >> 2)) * C_DIM + (lane & 3) * 8;

    f32x4 acc[4][4] = {};

    QKV_STAGE(0, 0);
    WAIT_AND_BARRIER();

    for (int k0 = 0; k0 < C_DIM; k0 += 128) {
        QKV_STAGE(1, k0 + 64);
        QKV_COMPUTE(0);
        WAIT_AND_BARRIER();
        if (k0 + 128 < C_DIM) QKV_STAGE(0, k0 + 128);
        QKV_COMPUTE(1);
        WAIT_AND_BARRIER();
    }

    const float scale = (colBase < C_DIM) ? CQ : 1.0f;   // Q region prescale (128 | 1024)
    #pragma unroll
    for (int ni = 0; ni < 4; ++ni) {
        int col = colBase + wn + ni * 16 + lo16;
        float bv = bias[col];
        #pragma unroll
        for (int mi = 0; mi < 4; ++mi) {
            int row0 = rowBase + wm + mi * 16 + quad * 4;
            #pragma unroll
            for (int r = 0; r < 4; ++r)
                qkv[(size_t)(row0 + r) * N_QKV + col] = (bf16)((acc[mi][ni][r] + bv) * scale);
        }
    }
}

// ---------------- flash attention v10: v8 + l-via-MFMA + early vf reads ----------------
// 512 blocks x 512 threads (8 waves). xcd=bid&7 runs ONLY heads {2*xcd, 2*xcd+1}.
// (a) l accumulated by 4 extra mfma16 with A=ones -> kills serial adds + epilogue shuffles;
// (b) vf ds_reads hoisted right after the ds_writes (in-order DS => RAW-safe) so PV's
// lgkm wait hides under prefetch-issue + QK + exp2.
__global__ __launch_bounds__(512, 2) void flash_kernel(
    const bf16* __restrict__ qkv,    // [T][3C]
    bf16* __restrict__ y)            // [T][C]
{
    __shared__ union {
        __align__(16) bf16 Vt[4][64][38];       // [w>>1][d][(w&1)*16 + s']
        float Ored[8][16][66];                  // [wave][d_local][q]
    } u;
    __shared__ float lred[8][64];

    const int bid = blockIdx.x;
    const int xcd = bid & 7, slot = bid >> 3;   // slot 0..63
    const int h = xcd * 2 + (slot & 1);
    const int qb = slot >> 1;                   // 0..31
    const int tid  = threadIdx.x;
    const int lane = tid & 63, w = tid >> 6;    // w in 0..7
    const int lo16 = lane & 15, quad = lane >> 4;

    bf16x8 qf[4][2];
    #pragma unroll
    for (int nq = 0; nq < 4; ++nq)
        #pragma unroll
        for (int dk = 0; dk < 2; ++dk)
            qf[nq][dk] = *(const bf16x8*)(qkv + (size_t)(qb * 64 + nq * 16 + lo16) * N_QKV
                                          + h * D_HEAD + dk * 32 + quad * 8);

    f32x4 o_t[4][4] = {};
    f32x4 o_l[4] = {};                          // l accumulated via MFMA ones-trick
    bf16x4 ones1;
    ones1[0] = (bf16)1.0f; ones1[1] = (bf16)1.0f; ones1[2] = (bf16)1.0f; ones1[3] = (bf16)1.0f;

    const bf16* kfb = qkv + (size_t)(w * 16 + lo16) * N_QKV + C_DIM + h * D_HEAD + quad * 8;
    const unsigned short* vb16 = (const unsigned short*)(qkv + 2 * C_DIM + h * D_HEAD);

    bf16x8 kf0 = *(const bf16x8*)(kfb);
    bf16x8 kf1 = *(const bf16x8*)(kfb + 32);
    unsigned short vreg[16];
    #pragma unroll
    for (int i = 0; i < 16; ++i)
        vreg[i] = vb16[(size_t)(w * 16 + i) * N_QKV + lane];

    bf16* vdst = &u.Vt[w >> 1][lane][(w & 1) * 16];

    for (int kt = 0; kt < T_DIM / 128; ++kt) {
        union { bf16x8 v; unsigned short us[8]; } p0, p1;
        #pragma unroll
        for (int i = 0; i < 8; ++i) { p0.us[i] = vreg[i]; p1.us[i] = vreg[8 + i]; }
        *(bf16x8*)vdst       = p0.v;
        *(bf16x8*)(vdst + 8) = p1.v;

        // early V-fragment reads: in-order DS makes these RAW-safe; their latency
        // hides under the prefetch issue + QK MFMA + exp2 below.
        bf16x4 vf[4];
        #pragma unroll
        for (int mi = 0; mi < 4; ++mi)
            vf[mi] = *(const bf16x4*)&u.Vt[w >> 1][mi * 16 + lo16][(w & 1) * 16 + quad * 4];

        bf16x8 nkf0 = kf0, nkf1 = kf1;
        if (kt + 1 < T_DIM / 128) {
            const bf16* kp = kfb + (size_t)(kt + 1) * 128 * N_QKV;
            nkf0 = *(const bf16x8*)(kp);
            nkf1 = *(const bf16x8*)(kp + 32);
            #pragma unroll
            for (int i = 0; i < 16; ++i)
                vreg[i] = vb16[(size_t)((kt + 1) * 128 + w * 16 + i) * N_QKV + lane];
        }

        f32x4 st[4];
        #pragma unroll
        for (int nq = 0; nq < 4; ++nq) {
            f32x4 z = {};
            z = __builtin_amdgcn_mfma_f32_16x16x32_bf16(kf0, qf[nq][0], z, 0, 0, 0);
            st[nq] = __builtin_amdgcn_mfma_f32_16x16x32_bf16(kf1, qf[nq][1], z, 0, 0, 0);
        }

        bf16x4 pb[4];
        #pragma unroll
        for (int nq = 0; nq < 4; ++nq)
            #pragma unroll
            for (int r = 0; r < 4; ++r)
                pb[nq][r] = (bf16)__builtin_amdgcn_exp2f(st[nq][r]);

        __builtin_amdgcn_s_setprio(1);
        #pragma unroll
        for (int nq = 0; nq < 4; ++nq)
            o_l[nq] = mfma16(ones1, pb[nq], o_l[nq]);
        #pragma unroll
        for (int mi = 0; mi < 4; ++mi)
            #pragma unroll
            for (int nq = 0; nq < 4; ++nq)
                o_t[mi][nq] = mfma16(vf[mi], pb[nq], o_t[mi][nq]);
        __builtin_amdgcn_s_setprio(0);

        kf0 = nkf0; kf1 = nkf1;
    }

    // o_l[nq][r] already holds sum over this wave's 16 keys for q = nq*16+lo16
    // (all r identical) -> no cross-lane reduce needed.
    #pragma unroll
    for (int nq = 0; nq < 4; ++nq)
        if (quad == 0) lred[w][nq * 16 + lo16] = o_l[nq][0];

    const int q8 = tid >> 3, dh = tid & 7;
    float linv = 0.f;
    #pragma unroll
    for (int mi = 0; mi < 4; ++mi) {
        __syncthreads();
        #pragma unroll
        for (int nq = 0; nq < 4; ++nq)
            #pragma unroll
            for (int r = 0; r < 4; ++r)
                u.Ored[w][quad * 4 + r][nq * 16 + lo16] = o_t[mi][nq][r];
        __syncthreads();
        if (mi == 0) {
            float ls = 0.f;
            #pragma unroll
            for (int j = 0; j < 8; ++j) ls += lred[j][q8];
            linv = 1.0f / ls;
        }
        bf16x2 ov;
        #pragma unroll
        for (int dj = 0; dj < 2; ++dj) {
            int d = dh * 2 + dj;
            float s = 0.f;
            #pragma unroll
            for (int j = 0; j < 8; ++j) s += u.Ored[j][d][q8];
            ov[dj] = (bf16)(s * linv);
        }
        *(bf16x2*)&y[(size_t)(qb * 64 + q8) * C_DIM + h * D_HEAD + mi * 16 + dh * 2] = ov;
    }
}

// ---------------- proj GEMM 64x64, BK=64, 2-phase DMA pipeline ----------------
#define PROJ_STAGE(BUF, K0) do {                                             \
    lds_load16(ga + (K0),      &As[BUF][0][(w * 16) * 32]);                  \
    lds_load16(ga + (K0) + 32, &As[BUF][1][(w * 16) * 32]);                  \
    lds_load16(gb + (K0),      &Bs[BUF][0][(w * 16) * 32]);                  \
    lds_load16(gb + (K0) + 32, &Bs[BUF][1][(w * 16) * 32]);                  \
} while (0)

#define PROJ_COMPUTE(BUF) do {                                               \
    _Pragma("unroll")                                                        \
    for (int p = 0; p < 2; ++p) {                                            \
        bf16x8 af[2], bfr[2];                                                \
        _Pragma("unroll")                                                    \
        for (int mi = 0; mi < 2; ++mi) af[mi]  = *(const bf16x8*)&As[BUF][p][(wm + mi * 16 + lo16) * 32 + quad * 8]; \
        _Pragma("unroll")                                                    \
        for (int ni = 0; ni < 2; ++ni) bfr[ni] = *(const bf16x8*)&Bs[BUF][p][(wn + ni * 16 + lo16) * 32 + quad * 8]; \
        _Pragma("unroll")                                                    \
        for (int mi = 0; mi < 2; ++mi)                                       \
            _Pragma("unroll")                                                \
            for (int ni = 0; ni < 2; ++ni)                                   \
                acc[mi][ni] = __builtin_amdgcn_mfma_f32_16x16x32_bf16(af[mi], bfr[ni], acc[mi][ni], 0, 0, 0); \
    }                                                                        \
} while (0)

__global__ __launch_bounds__(256, 4) void proj_gemm_kernel(
    const bf16* __restrict__ A, const bf16* __restrict__ Bt,
    const float* __restrict__ bias, float* __restrict__ out)
{
    __shared__ __align__(16) bf16 As[2][2][64 * 32];
    __shared__ __align__(16) bf16 Bs[2][2][64 * 32];
    const int bid = blockIdx.x;
    const int xcd = bid & 7, slot = bid >> 3;            // slot 0..63
    const int colBase = (xcd * 2 + (slot & 1)) * 64;
    const int rowBase = (slot >> 1) * 64;
    const int tid = threadIdx.x, lane = tid & 63, w = tid >> 6;
    const int lo16 = lane & 15, quad = lane >> 4;
    const int wm = (w & 1) * 32, wn = (w >> 1) * 32;

    const bf16* ga = A  + (size_t)(rowBase + w * 16 + (lane >> 2)) * C_DIM + (lane & 3) * 8;
    const bf16* gb = Bt + (size_t)(colBase + w * 16 + (lane >> 2)) * C_DIM + (lane & 3) * 8;

    f32x4 acc[2][2] = {};

    PROJ_STAGE(0, 0);
    WAIT_AND_BARRIER();

    for (int k0 = 0; k0 < C_DIM; k0 += 128) {
        PROJ_STAGE(1, k0 + 64);
        PROJ_COMPUTE(0);
        WAIT_AND_BARRIER();
        if (k0 + 128 < C_DIM) PROJ_STAGE(0, k0 + 128);
        PROJ_COMPUTE(1);
        WAIT_AND_BARRIER();
    }

    #pragma unroll
    for (int ni = 0; ni < 2; ++ni) {
        int col = colBase + wn + ni * 16 + lo16;
        float bv = bias[col];
        #pragma unroll
        for (int mi = 0; mi < 2; ++mi) {
            int row0 = rowBase + wm + mi * 16 + quad * 4;
            #pragma unroll
            for (int r = 0; r < 4; ++r)
                out[(size_t)(row0 + r) * C_DIM + col] = acc[mi][ni][r] + bv;
        }
    }
}

extern "C" void kernel_launch(void* const* d_in, const int* in_sizes, int n_in,
                              void* d_out, int out_size, void* d_ws, size_t ws_size,
                              hipStream_t stream) {
    const float* x      = (const float*)d_in[0];
    const float* W_qkv  = (const float*)d_in[1];
    const float* b_qkv  = (const float*)d_in[2];
    const float* W_proj = (const float*)d_in[3];
    const float* b_proj = (const float*)d_in[4];
    float* out = (float*)d_out;

    char* ws = (char*)d_ws;
    bf16* xb      = (bf16*)(ws);                 // [0,4) MB
    bf16* Wqkv_t  = (bf16*)(ws + (4  << 20));    // [4,10) MB
    bf16* Wproj_t = (bf16*)(ws + (10 << 20));    // [10,12) MB
    bf16* qkv_bf  = (bf16*)(ws + (12 << 20));    // [12,24) MB  interleaved [T][3072], Q prescaled
    bf16* yb      = (bf16*)(ws + (24 << 20));    // [24,28) MB

    prep_kernel<<<5120, 256, 0, stream>>>(x, xb, W_qkv, Wqkv_t, W_proj, Wproj_t);

    qkv_gemm_kernel<<<384, 256, 0, stream>>>(xb, Wqkv_t, b_qkv, qkv_bf);

    flash_kernel<<<512, 512, 0, stream>>>(qkv_bf, yb);

    proj_gemm_kernel<<<512, 256, 0, stream>>>(yb, Wproj_t, b_proj, out);
}

// Round 12
// 144.846 us; speedup vs baseline: 1.0225x; 1.0003x over previous
//
#include <hip/hip_runtime.h>
#include <hip/hip_bf16.h>
#include <stdint.h>

#define T_DIM 2048
#define C_DIM 1024
#define H_DIM 16
#define D_HEAD 64
#define N_QKV 3072
#define CQ 0.18033688011112042f   // log2(e)/8

typedef __bf16 bf16;
typedef __bf16 bf16x8 __attribute__((ext_vector_type(8)));
typedef __bf16 bf16x4 __attribute__((ext_vector_type(4)));
typedef __bf16 bf16x2 __attribute__((ext_vector_type(2)));
typedef float f32x4 __attribute__((ext_vector_type(4)));
typedef short s16x4 __attribute__((ext_vector_type(4)));

__device__ __forceinline__ void lds_load16(const void* g, void* l) {
    __builtin_amdgcn_global_load_lds(
        (const __attribute__((address_space(1))) void*)g,
        (__attribute__((address_space(3))) void*)l, 16, 0, 0);
}

__device__ __forceinline__ f32x4 mfma16(bf16x4 a, bf16x4 b, f32x4 c) {
#if __has_builtin(__builtin_amdgcn_mfma_f32_16x16x16_bf16)
    return __builtin_amdgcn_mfma_f32_16x16x16_bf16(a, b, c, 0, 0, 0);
#elif __has_builtin(__builtin_amdgcn_mfma_f32_16x16x16bf16_1k)
    union { bf16x4 v; s16x4 s; } ua, ub;
    ua.v = a; ub.v = b;
    return __builtin_amdgcn_mfma_f32_16x16x16bf16_1k(ua.s, ub.s, c, 0, 0, 0);
#else
    asm volatile("v_mfma_f32_16x16x16_bf16 %0, %1, %2, %0"
                 : "+v"(c) : "v"(a), "v"(b));
    return c;
#endif
}

// ---- prep: blocks 0..1023 cast x; blocks 1024..4095 transpose W_qkv ----
// (W_proj transpose moved into qkv_gemm's tail blocks: qkv runs 384 blocks at
// 2-blocks/CU capacity = 128 idle CU-slots for its whole window; the transpose
// backfills those instead of occupying serial prep time.)
__global__ void prep_kernel(const float* __restrict__ x, bf16* __restrict__ xb,
                            const float* __restrict__ Wq, bf16* __restrict__ WqT) {
    __shared__ float tile[32][33];
    int bid = blockIdx.x;
    int t = threadIdx.x;
    if (bid < 1024) {
        int i = (bid * 256 + t) * 8;
        float4 a = *(const float4*)(x + i);
        float4 b = *(const float4*)(x + i + 4);
        bf16x8 o;
        o[0] = (bf16)a.x; o[1] = (bf16)a.y; o[2] = (bf16)a.z; o[3] = (bf16)a.w;
        o[4] = (bf16)b.x; o[5] = (bf16)b.y; o[6] = (bf16)b.z; o[7] = (bf16)b.w;
        *(bf16x8*)(xb + i) = o;
        return;
    }
    bid -= 1024;                                   // 0..3071: W_qkv 32x32 tiles
    int nb = (bid % 96) * 32, kb = (bid / 96) * 32;
    int r = t >> 3, c4 = (t & 7) * 4;
    float4 v = *(const float4*)(Wq + (size_t)(kb + r) * N_QKV + nb + c4);
    tile[r][c4 + 0] = v.x; tile[r][c4 + 1] = v.y;
    tile[r][c4 + 2] = v.z; tile[r][c4 + 3] = v.w;
    __syncthreads();
    bf16x4 ov;
    ov[0] = (bf16)tile[c4 + 0][r]; ov[1] = (bf16)tile[c4 + 1][r];
    ov[2] = (bf16)tile[c4 + 2][r]; ov[3] = (bf16)tile[c4 + 3][r];
    *(bf16x4*)(WqT + (size_t)(nb + r) * C_DIM + kb + c4) = ov;
}

// ---------------- QKV GEMM 128x128, BK=64, 2-phase DMA pipeline, XCD-swizzled ----------------
// bid < 384: GEMM (unchanged from the 144.9us config). bid 384..639: W_proj transpose
// (64x64 tiles, 256-thread pattern verified in r10) filling qkv's 128 idle CU-slots.
#define QKV_STAGE(BUF, K0) do {                                                      \
    lds_load16(ga + (K0),                            &As[BUF][0][(w * 16) * 32]);    \
    lds_load16(ga + (K0) + 32,                       &As[BUF][1][(w * 16) * 32]);    \
    lds_load16(ga + (size_t)64 * C_DIM + (K0),       &As[BUF][0][(64 + w * 16) * 32]); \
    lds_load16(ga + (size_t)64 * C_DIM + (K0) + 32,  &As[BUF][1][(64 + w * 16) * 32]); \
    lds_load16(gb + (K0),                            &Bs[BUF][0][(w * 16) * 32]);    \
    lds_load16(gb + (K0) + 32,                       &Bs[BUF][1][(w * 16) * 32]);    \
    lds_load16(gb + (size_t)64 * C_DIM + (K0),       &Bs[BUF][0][(64 + w * 16) * 32]); \
    lds_load16(gb + (size_t)64 * C_DIM + (K0) + 32,  &Bs[BUF][1][(64 + w * 16) * 32]); \
} while (0)

#define QKV_COMPUTE(BUF) do {                                                \
    _Pragma("unroll")                                                        \
    for (int p = 0; p < 2; ++p) {                                            \
        bf16x8 af[4], bfr[4];                                                \
        _Pragma("unroll")                                                    \
        for (int mi = 0; mi < 4; ++mi) af[mi]  = *(const bf16x8*)&As[BUF][p][(wm + mi * 16 + lo16) * 32 + quad * 8]; \
        _Pragma("unroll")                                                    \
        for (int ni = 0; ni < 4; ++ni) bfr[ni] = *(const bf16x8*)&Bs[BUF][p][(wn + ni * 16 + lo16) * 32 + quad * 8]; \
        _Pragma("unroll")                                                    \
        for (int mi = 0; mi < 4; ++mi)                                       \
            _Pragma("unroll")                                                \
            for (int ni = 0; ni < 4; ++ni)                                   \
                acc[mi][ni] = __builtin_amdgcn_mfma_f32_16x16x32_bf16(af[mi], bfr[ni], acc[mi][ni], 0, 0, 0); \
    }                                                                        \
} while (0)

#define WAIT_AND_BARRIER() do {                                              \
    asm volatile("s_waitcnt vmcnt(0)" ::: "memory");                         \
    __builtin_amdgcn_s_barrier();                                            \
} while (0)

__global__ __launch_bounds__(256, 2) void qkv_gemm_kernel(
    const bf16* __restrict__ A, const bf16* __restrict__ Bt,
    const float* __restrict__ bias, bf16* __restrict__ qkv,
    const float* __restrict__ Wp, bf16* __restrict__ WpT)
{
    __shared__ union {
        struct {
            __align__(16) bf16 As[2][2][128 * 32];
            __align__(16) bf16 Bs[2][2][128 * 32];
        } g;
        float tile[64][65];                      // W_proj transpose staging
    } u;
    const int bid = blockIdx.x;
    const int tid = threadIdx.x;

    if (bid >= 384) {
        // ---- W_proj transpose: 256 tiles of 64x64 (16 col x 16 k), 256 threads ----
        int b2 = bid - 384;
        int nb = (b2 & 15) * 64, kb = (b2 >> 4) * 64;
        {
            int r = tid >> 2, c16 = (tid & 3) * 16;   // 4 lanes x 64B per row
            const float* src = Wp + (size_t)(kb + r) * C_DIM + nb + c16;
            #pragma unroll
            for (int j = 0; j < 4; ++j) {
                float4 v = *(const float4*)(src + j * 4);
                u.tile[r][c16 + j * 4 + 0] = v.x; u.tile[r][c16 + j * 4 + 1] = v.y;
                u.tile[r][c16 + j * 4 + 2] = v.z; u.tile[r][c16 + j * 4 + 3] = v.w;
            }
        }
        __syncthreads();
        {
            int n = tid >> 2, s = (tid & 3) * 16;     // 4 lanes x 32B per out-row
            bf16x8 o0, o1;
            #pragma unroll
            for (int j = 0; j < 8; ++j) { o0[j] = (bf16)u.tile[s + j][n]; o1[j] = (bf16)u.tile[s + 8 + j][n]; }
            bf16* dst = WpT + (size_t)(nb + n) * C_DIM + kb + s;
            *(bf16x8*)(dst)     = o0;
            *(bf16x8*)(dst + 8) = o1;
        }
        return;
    }

    auto& As = u.g.As;
    auto& Bs = u.g.Bs;
    const int xcd = bid & 7, slot = bid >> 3;            // slot 0..47
    const int rowBase = (slot / 3) * 128;                // 16 row-blocks
    const int colBase = (xcd * 3 + (slot % 3)) * 128;    // 24 col-blocks
    const int lane = tid & 63, w = tid >> 6;
    const int lo16 = lane & 15, quad = lane >> 4;
    const int wm = (w & 1) * 64, wn = (w >> 1) * 64;

    const bf16* ga = A  + (size_t)(rowBase + w * 16 + (lane >> 2)) * C_DIM + (lane & 3) * 8;
    const bf16* gb = Bt + (size_t)(colBase + w * 16 + (lane >> 2)) * C_DIM + (lane & 3) * 8;

    f32x4 acc[4][4] = {};

    QKV_STAGE(0, 0);
    WAIT_AND_BARRIER();

    for (int k0 = 0; k0 < C_DIM; k0 += 128) {
        QKV_STAGE(1, k0 + 64);
        QKV_COMPUTE(0);
        WAIT_AND_BARRIER();
        if (k0 + 128 < C_DIM) QKV_STAGE(0, k0 + 128);
        QKV_COMPUTE(1);
        WAIT_AND_BARRIER();
    }

    const float scale = (colBase < C_DIM) ? CQ : 1.0f;   // Q region prescale (128 | 1024)
    #pragma unroll
    for (int ni = 0; ni < 4; ++ni) {
        int col = colBase + wn + ni * 16 + lo16;
        float bv = bias[col];
        #pragma unroll
        for (int mi = 0; mi < 4; ++mi) {
            int row0 = rowBase + wm + mi * 16 + quad * 4;
            #pragma unroll
            for (int r = 0; r < 4; ++r)
                qkv[(size_t)(row0 + r) * N_QKV + col] = (bf16)((acc[mi][ni][r] + bv) * scale);
        }
    }
}

// ---------------- flash attention v10 (unchanged, best measured) ----------------
// 512 blocks x 512 threads (8 waves). xcd=bid&7 runs ONLY heads {2*xcd, 2*xcd+1}.
// (a) l accumulated by 4 extra mfma16 with A=ones; (b) vf ds_reads hoisted right
// after ds_writes (in-order DS => RAW-safe) so PV's lgkm wait hides under
// prefetch-issue + QK + exp2.
__global__ __launch_bounds__(512, 2) void flash_kernel(
    const bf16* __restrict__ qkv,    // [T][3C]
    bf16* __restrict__ y)            // [T][C]
{
    __shared__ union {
        __align__(16) bf16 Vt[4][64][38];       // [w>>1][d][(w&1)*16 + s']
        float Ored[8][16][66];                  // [wave][d_local][q]
    } u;
    __shared__ float lred[8][64];

    const int bid = blockIdx.x;
    const int xcd = bid & 7, slot = bid >> 3;   // slot 0..63
    const int h = xcd * 2 + (slot & 1);
    const int qb = slot >> 1;                   // 0..31
    const int tid  = threadIdx.x;
    const int lane = tid & 63, w = tid >> 6;    // w in 0..7
    const int lo16 = lane & 15, quad = lane >> 4;

    bf16x8 qf[4][2];
    #pragma unroll
    for (int nq = 0; nq < 4; ++nq)
        #pragma unroll
        for (int dk = 0; dk < 2; ++dk)
            qf[nq][dk] = *(const bf16x8*)(qkv + (size_t)(qb * 64 + nq * 16 + lo16) * N_QKV
                                          + h * D_HEAD + dk * 32 + quad * 8);

    f32x4 o_t[4][4] = {};
    f32x4 o_l[4] = {};                          // l accumulated via MFMA ones-trick
    bf16x4 ones1;
    ones1[0] = (bf16)1.0f; ones1[1] = (bf16)1.0f; ones1[2] = (bf16)1.0f; ones1[3] = (bf16)1.0f;

    const bf16* kfb = qkv + (size_t)(w * 16 + lo16) * N_QKV + C_DIM + h * D_HEAD + quad * 8;
    const unsigned short* vb16 = (const unsigned short*)(qkv + 2 * C_DIM + h * D_HEAD);

    bf16x8 kf0 = *(const bf16x8*)(kfb);
    bf16x8 kf1 = *(const bf16x8*)(kfb + 32);
    unsigned short vreg[16];
    #pragma unroll
    for (int i = 0; i < 16; ++i)
        vreg[i] = vb16[(size_t)(w * 16 + i) * N_QKV + lane];

    bf16* vdst = &u.Vt[w >> 1][lane][(w & 1) * 16];

    for (int kt = 0; kt < T_DIM / 128; ++kt) {
        union { bf16x8 v; unsigned short us[8]; } p0, p1;
        #pragma unroll
        for (int i = 0; i < 8; ++i) { p0.us[i] = vreg[i]; p1.us[i] = vreg[8 + i]; }
        *(bf16x8*)vdst       = p0.v;
        *(bf16x8*)(vdst + 8) = p1.v;

        // early V-fragment reads: in-order DS makes these RAW-safe; their latency
        // hides under the prefetch issue + QK MFMA + exp2 below.
        bf16x4 vf[4];
        #pragma unroll
        for (int mi = 0; mi < 4; ++mi)
            vf[mi] = *(const bf16x4*)&u.Vt[w >> 1][mi * 16 + lo16][(w & 1) * 16 + quad * 4];

        bf16x8 nkf0 = kf0, nkf1 = kf1;
        if (kt + 1 < T_DIM / 128) {
            const bf16* kp = kfb + (size_t)(kt + 1) * 128 * N_QKV;
            nkf0 = *(const bf16x8*)(kp);
            nkf1 = *(const bf16x8*)(kp + 32);
            #pragma unroll
            for (int i = 0; i < 16; ++i)
                vreg[i] = vb16[(size_t)((kt + 1) * 128 + w * 16 + i) * N_QKV + lane];
        }

        f32x4 st[4];
        #pragma unroll
        for (int nq = 0; nq < 4; ++nq) {
            f32x4 z = {};
            z = __builtin_amdgcn_mfma_f32_16x16x32_bf16(kf0, qf[nq][0], z, 0, 0, 0);
            st[nq] = __builtin_amdgcn_mfma_f32_16x16x32_bf16(kf1, qf[nq][1], z, 0, 0, 0);
        }

        bf16x4 pb[4];
        #pragma unroll
        for (int nq = 0; nq < 4; ++nq)
            #pragma unroll
            for (int r = 0; r < 4; ++r)
                pb[nq][r] = (bf16)__builtin_amdgcn_exp2f(st[nq][r]);

        __builtin_amdgcn_s_setprio(1);
        #pragma unroll
        for (int nq = 0; nq < 4; ++nq)
            o_l[nq] = mfma16(ones1, pb[nq], o_l[nq]);
        #pragma unroll
        for (int mi = 0; mi < 4; ++mi)
            #pragma unroll
            for (int nq = 0; nq < 4; ++nq)
                o_t[mi][nq] = mfma16(vf[mi], pb[nq], o_t[mi][nq]);
        __builtin_amdgcn_s_setprio(0);

        kf0 = nkf0; kf1 = nkf1;
    }

    // o_l[nq][r] holds sum over this wave's 16 keys for q = nq*16+lo16
    #pragma unroll
    for (int nq = 0; nq < 4; ++nq)
        if (quad == 0) lred[w][nq * 16 + lo16] = o_l[nq][0];

    const int q8 = tid >> 3, dh = tid & 7;
    float linv = 0.f;
    #pragma unroll
    for (int mi = 0; mi < 4; ++mi) {
        __syncthreads();
        #pragma unroll
        for (int nq = 0; nq < 4; ++nq)
            #pragma unroll
            for (int r = 0; r < 4; ++r)
                u.Ored[w][quad * 4 + r][nq * 16 + lo16] = o_t[mi][nq][r];
        __syncthreads();
        if (mi == 0) {
            float ls = 0.f;
            #pragma unroll
            for (int j = 0; j < 8; ++j) ls += lred[j][q8];
            linv = 1.0f / ls;
        }
        bf16x2 ov;
        #pragma unroll
        for (int dj = 0; dj < 2; ++dj) {
            int d = dh * 2 + dj;
            float s = 0.f;
            #pragma unroll
            for (int j = 0; j < 8; ++j) s += u.Ored[j][d][q8];
            ov[dj] = (bf16)(s * linv);
        }
        *(bf16x2*)&y[(size_t)(qb * 64 + q8) * C_DIM + h * D_HEAD + mi * 16 + dh * 2] = ov;
    }
}

// ---------------- proj GEMM 64x64, BK=64, 2-phase DMA pipeline ----------------
#define PROJ_STAGE(BUF, K0) do {                                             \
    lds_load16(ga + (K0),      &As[BUF][0][(w * 16) * 32]);                  \
    lds_load16(ga + (K0) + 32, &As[BUF][1][(w * 16) * 32]);                  \
    lds_load16(gb + (K0),      &Bs[BUF][0][(w * 16) * 32]);                  \
    lds_load16(gb + (K0) + 32, &Bs[BUF][1][(w * 16) * 32]);                  \
} while (0)

#define PROJ_COMPUTE(BUF) do {                                               \
    _Pragma("unroll")                                                        \
    for (int p = 0; p < 2; ++p) {                                            \
        bf16x8 af[2], bfr[2];                                                \
        _Pragma("unroll")                                                    \
        for (int mi = 0; mi < 2; ++mi) af[mi]  = *(const bf16x8*)&As[BUF][p][(wm + mi * 16 + lo16) * 32 + quad * 8]; \
        _Pragma("unroll")                                                    \
        for (int ni = 0; ni < 2; ++ni) bfr[ni] = *(const bf16x8*)&Bs[BUF][p][(wn + ni * 16 + lo16) * 32 + quad * 8]; \
        _Pragma("unroll")                                                    \
        for (int mi = 0; mi < 2; ++mi)                                       \
            _Pragma("unroll")                                                \
            for (int ni = 0; ni < 2; ++ni)                                   \
                acc[mi][ni] = __builtin_amdgcn_mfma_f32_16x16x32_bf16(af[mi], bfr[ni], acc[mi][ni], 0, 0, 0); \
    }                                                                        \
} while (0)

__global__ __launch_bounds__(256, 4) void proj_gemm_kernel(
    const bf16* __restrict__ A, const bf16* __restrict__ Bt,
    const float* __restrict__ bias, float* __restrict__ out)
{
    __shared__ __align__(16) bf16 As[2][2][64 * 32];
    __shared__ __align__(16) bf16 Bs[2][2][64 * 32];
    const int bid = blockIdx.x;
    const int xcd = bid & 7, slot = bid >> 3;            // slot 0..63
    const int colBase = (xcd * 2 + (slot & 1)) * 64;
    const int rowBase = (slot >> 1) * 64;
    const int tid = threadIdx.x, lane = tid & 63, w = tid >> 6;
    const int lo16 = lane & 15, quad = lane >> 4;
    const int wm = (w & 1) * 32, wn = (w >> 1) * 32;

    const bf16* ga = A  + (size_t)(rowBase + w * 16 + (lane >> 2)) * C_DIM + (lane & 3) * 8;
    const bf16* gb = Bt + (size_t)(colBase + w * 16 + (lane >> 2)) * C_DIM + (lane & 3) * 8;

    f32x4 acc[2][2] = {};

    PROJ_STAGE(0, 0);
    WAIT_AND_BARRIER();

    for (int k0 = 0; k0 < C_DIM; k0 += 128) {
        PROJ_STAGE(1, k0 + 64);
        PROJ_COMPUTE(0);
        WAIT_AND_BARRIER();
        if (k0 + 128 < C_DIM) PROJ_STAGE(0, k0 + 128);
        PROJ_COMPUTE(1);
        WAIT_AND_BARRIER();
    }

    #pragma unroll
    for (int ni = 0; ni < 2; ++ni) {
        int col = colBase + wn + ni * 16 + lo16;
        float bv = bias[col];
        #pragma unroll
        for (int mi = 0; mi < 2; ++mi) {
            int row0 = rowBase + wm + mi * 16 + quad * 4;
            #pragma unroll
            for (int r = 0; r < 4; ++r)
                out[(size_t)(row0 + r) * C_DIM + col] = acc[mi][ni][r] + bv;
        }
    }
}

extern "C" void kernel_launch(void* const* d_in, const int* in_sizes, int n_in,
                              void* d_out, int out_size, void* d_ws, size_t ws_size,
                              hipStream_t stream) {
    const float* x      = (const float*)d_in[0];
    const float* W_qkv  = (const float*)d_in[1];
    const float* b_qkv  = (const float*)d_in[2];
    const float* W_proj = (const float*)d_in[3];
    const float* b_proj = (const float*)d_in[4];
    float* out = (float*)d_out;

    char* ws = (char*)d_ws;
    bf16* xb      = (bf16*)(ws);                 // [0,4) MB
    bf16* Wqkv_t  = (bf16*)(ws + (4  << 20));    // [4,10) MB
    bf16* Wproj_t = (bf16*)(ws + (10 << 20));    // [10,12) MB
    bf16* qkv_bf  = (bf16*)(ws + (12 << 20));    // [12,24) MB  interleaved [T][3072], Q prescaled
    bf16* yb      = (bf16*)(ws + (24 << 20));    // [24,28) MB

    prep_kernel<<<4096, 256, 0, stream>>>(x, xb, W_qkv, Wqkv_t);

    qkv_gemm_kernel<<<640, 256, 0, stream>>>(xb, Wqkv_t, b_qkv, qkv_bf, W_proj, Wproj_t);

    flash_kernel<<<512, 512, 0, stream>>>(qkv_bf, yb);

    proj_gemm_kernel<<<512, 256, 0, stream>>>(yb, Wproj_t, b_proj, out);
}

// Round 13
// 142.138 us; speedup vs baseline: 1.0420x; 1.0191x over previous
//
#include <hip/hip_runtime.h>
#include <hip/hip_bf16.h>
#include <stdint.h>

#define T_DIM 2048
#define C_DIM 1024
#define H_DIM 16
#define D_HEAD 64
#define N_QKV 3072
#define CQ 0.18033688011112042f   // log2(e)/8

typedef __bf16 bf16;
typedef __bf16 bf16x8 __attribute__((ext_vector_type(8)));
typedef __bf16 bf16x4 __attribute__((ext_vector_type(4)));
typedef __bf16 bf16x2 __attribute__((ext_vector_type(2)));
typedef float f32x4 __attribute__((ext_vector_type(4)));
typedef short s16x4 __attribute__((ext_vector_type(4)));

__device__ __forceinline__ void lds_load16(const void* g, void* l) {
    __builtin_amdgcn_global_load_lds(
        (const __attribute__((address_space(1))) void*)g,
        (__attribute__((address_space(3))) void*)l, 16, 0, 0);
}

__device__ __forceinline__ f32x4 mfma16(bf16x4 a, bf16x4 b, f32x4 c) {
#if __has_builtin(__builtin_amdgcn_mfma_f32_16x16x16_bf16)
    return __builtin_amdgcn_mfma_f32_16x16x16_bf16(a, b, c, 0, 0, 0);
#elif __has_builtin(__builtin_amdgcn_mfma_f32_16x16x16bf16_1k)
    union { bf16x4 v; s16x4 s; } ua, ub;
    ua.v = a; ub.v = b;
    return __builtin_amdgcn_mfma_f32_16x16x16bf16_1k(ua.s, ub.s, c, 0, 0, 0);
#else
    asm volatile("v_mfma_f32_16x16x16_bf16 %0, %1, %2, %0"
                 : "+v"(c) : "v"(a), "v"(b));
    return c;
#endif
}

// ---- prep: blocks 0..1023 cast x; blocks 1024..4095 transpose W_qkv ----
__global__ void prep_kernel(const float* __restrict__ x, bf16* __restrict__ xb,
                            const float* __restrict__ Wq, bf16* __restrict__ WqT) {
    __shared__ float tile[32][33];
    int bid = blockIdx.x;
    int t = threadIdx.x;
    if (bid < 1024) {
        int i = (bid * 256 + t) * 8;
        float4 a = *(const float4*)(x + i);
        float4 b = *(const float4*)(x + i + 4);
        bf16x8 o;
        o[0] = (bf16)a.x; o[1] = (bf16)a.y; o[2] = (bf16)a.z; o[3] = (bf16)a.w;
        o[4] = (bf16)b.x; o[5] = (bf16)b.y; o[6] = (bf16)b.z; o[7] = (bf16)b.w;
        *(bf16x8*)(xb + i) = o;
        return;
    }
    bid -= 1024;                                   // 0..3071: W_qkv 32x32 tiles
    int nb = (bid % 96) * 32, kb = (bid / 96) * 32;
    int r = t >> 3, c4 = (t & 7) * 4;
    float4 v = *(const float4*)(Wq + (size_t)(kb + r) * N_QKV + nb + c4);
    tile[r][c4 + 0] = v.x; tile[r][c4 + 1] = v.y;
    tile[r][c4 + 2] = v.z; tile[r][c4 + 3] = v.w;
    __syncthreads();
    bf16x4 ov;
    ov[0] = (bf16)tile[c4 + 0][r]; ov[1] = (bf16)tile[c4 + 1][r];
    ov[2] = (bf16)tile[c4 + 2][r]; ov[3] = (bf16)tile[c4 + 3][r];
    *(bf16x4*)(WqT + (size_t)(nb + r) * C_DIM + kb + c4) = ov;
}

// ---------------- QKV GEMM 128x96, BK=64, 2-phase DMA pipeline, XCD-swizzled ----------------
// v5: PERFECT FILL. 512 GEMM blocks (16 row x 32 col of 96) = exactly 2 blocks/CU on all
// 256 CUs. Previous 384x(128x128) left half the CUs with 1 block -> wall = 2.0 big-block
// times on the doubly-loaded CUs; now wall = 2 x 0.75 = 1.5 equivalents (-25%).
// 96 % 1024 != 0 -> tiles straddle the Q/K boundary: Q-prescale applied PER COLUMN.
// bid 512..767: W_proj transpose tail (r10/r12-verified 64x64 tile code).
#define QKV_STAGE(BUF, K0) do {                                                      \
    lds_load16(ga + (K0),                            &As[BUF][0][(w * 16) * 32]);    \
    lds_load16(ga + (K0) + 32,                       &As[BUF][1][(w * 16) * 32]);    \
    lds_load16(ga + (size_t)64 * C_DIM + (K0),       &As[BUF][0][(64 + w * 16) * 32]); \
    lds_load16(ga + (size_t)64 * C_DIM + (K0) + 32,  &As[BUF][1][(64 + w * 16) * 32]); \
    lds_load16(gb + (K0),                            &Bs[BUF][0][(w * 16) * 32]);    \
    lds_load16(gb + (K0) + 32,                       &Bs[BUF][1][(w * 16) * 32]);    \
    if (w < 2) {                                                                     \
        lds_load16(gb + (size_t)64 * C_DIM + (K0),      &Bs[BUF][0][(64 + w * 16) * 32]); \
        lds_load16(gb + (size_t)64 * C_DIM + (K0) + 32, &Bs[BUF][1][(64 + w * 16) * 32]); \
    }                                                                                \
} while (0)

#define QKV_COMPUTE(BUF) do {                                                \
    _Pragma("unroll")                                                        \
    for (int p = 0; p < 2; ++p) {                                            \
        bf16x8 af[4], bfr[3];                                                \
        _Pragma("unroll")                                                    \
        for (int mi = 0; mi < 4; ++mi) af[mi]  = *(const bf16x8*)&As[BUF][p][(wm + mi * 16 + lo16) * 32 + quad * 8]; \
        _Pragma("unroll")                                                    \
        for (int ni = 0; ni < 3; ++ni) bfr[ni] = *(const bf16x8*)&Bs[BUF][p][(wn + ni * 16 + lo16) * 32 + quad * 8]; \
        _Pragma("unroll")                                                    \
        for (int mi = 0; mi < 4; ++mi)                                       \
            _Pragma("unroll")                                                \
            for (int ni = 0; ni < 3; ++ni)                                   \
                acc[mi][ni] = __builtin_amdgcn_mfma_f32_16x16x32_bf16(af[mi], bfr[ni], acc[mi][ni], 0, 0, 0); \
    }                                                                        \
} while (0)

#define WAIT_AND_BARRIER() do {                                              \
    asm volatile("s_waitcnt vmcnt(0)" ::: "memory");                         \
    __builtin_amdgcn_s_barrier();                                            \
} while (0)

__global__ __launch_bounds__(256, 2) void qkv_gemm_kernel(
    const bf16* __restrict__ A, const bf16* __restrict__ Bt,
    const float* __restrict__ bias, bf16* __restrict__ qkv,
    const float* __restrict__ Wp, bf16* __restrict__ WpT)
{
    __shared__ union {
        struct {
            __align__(16) bf16 As[2][2][128 * 32];
            __align__(16) bf16 Bs[2][2][96 * 32];
        } g;
        float tile[64][65];                      // W_proj transpose staging
    } u;
    const int bid = blockIdx.x;
    const int tid = threadIdx.x;

    if (bid >= 512) {
        // ---- W_proj transpose: 256 tiles of 64x64 (16 col x 16 k), 256 threads ----
        int b2 = bid - 512;
        int nb = (b2 & 15) * 64, kb = (b2 >> 4) * 64;
        {
            int r = tid >> 2, c16 = (tid & 3) * 16;   // 4 lanes x 64B per row
            const float* src = Wp + (size_t)(kb + r) * C_DIM + nb + c16;
            #pragma unroll
            for (int j = 0; j < 4; ++j) {
                float4 v = *(const float4*)(src + j * 4);
                u.tile[r][c16 + j * 4 + 0] = v.x; u.tile[r][c16 + j * 4 + 1] = v.y;
                u.tile[r][c16 + j * 4 + 2] = v.z; u.tile[r][c16 + j * 4 + 3] = v.w;
            }
        }
        __syncthreads();
        {
            int n = tid >> 2, s = (tid & 3) * 16;     // 4 lanes x 32B per out-row
            bf16x8 o0, o1;
            #pragma unroll
            for (int j = 0; j < 8; ++j) { o0[j] = (bf16)u.tile[s + j][n]; o1[j] = (bf16)u.tile[s + 8 + j][n]; }
            bf16* dst = WpT + (size_t)(nb + n) * C_DIM + kb + s;
            *(bf16x8*)(dst)     = o0;
            *(bf16x8*)(dst + 8) = o1;
        }
        return;
    }

    auto& As = u.g.As;
    auto& Bs = u.g.Bs;
    const int xcd = bid & 7, slot = bid >> 3;            // slot 0..63
    const int rowBase = (slot >> 2) * 128;               // 16 row-blocks
    const int colBase = (xcd * 4 + (slot & 3)) * 96;     // 32 col-blocks of 96
    const int lane = tid & 63, w = tid >> 6;             // 4 waves
    const int lo16 = lane & 15, quad = lane >> 4;
    const int wm = (w & 1) * 64, wn = (w >> 1) * 48;     // 2m x 2n wave grid

    const bf16* ga = A  + (size_t)(rowBase + w * 16 + (lane >> 2)) * C_DIM + (lane & 3) * 8;
    const bf16* gb = Bt + (size_t)(colBase + w * 16 + (lane >> 2)) * C_DIM + (lane & 3) * 8;

    f32x4 acc[4][3] = {};

    QKV_STAGE(0, 0);
    WAIT_AND_BARRIER();

    for (int k0 = 0; k0 < C_DIM; k0 += 128) {
        QKV_STAGE(1, k0 + 64);
        QKV_COMPUTE(0);
        WAIT_AND_BARRIER();
        if (k0 + 128 < C_DIM) QKV_STAGE(0, k0 + 128);
        QKV_COMPUTE(1);
        WAIT_AND_BARRIER();
    }

    #pragma unroll
    for (int ni = 0; ni < 3; ++ni) {
        int col = colBase + wn + ni * 16 + lo16;
        const float scale = (col < C_DIM) ? CQ : 1.0f;   // per-col: 96-tiles straddle Q/K
        float bv = bias[col];
        #pragma unroll
        for (int mi = 0; mi < 4; ++mi) {
            int row0 = rowBase + wm + mi * 16 + quad * 4;
            #pragma unroll
            for (int r = 0; r < 4; ++r)
                qkv[(size_t)(row0 + r) * N_QKV + col] = (bf16)((acc[mi][ni][r] + bv) * scale);
        }
    }
}

// ---------------- flash attention v10 (unchanged, best measured) ----------------
// 512 blocks x 512 threads (8 waves). xcd=bid&7 runs ONLY heads {2*xcd, 2*xcd+1}.
// (a) l accumulated by 4 extra mfma16 with A=ones; (b) vf ds_reads hoisted right
// after ds_writes (in-order DS => RAW-safe) so PV's lgkm wait hides under
// prefetch-issue + QK + exp2.
__global__ __launch_bounds__(512, 2) void flash_kernel(
    const bf16* __restrict__ qkv,    // [T][3C]
    bf16* __restrict__ y)            // [T][C]
{
    __shared__ union {
        __align__(16) bf16 Vt[4][64][38];       // [w>>1][d][(w&1)*16 + s']
        float Ored[8][16][66];                  // [wave][d_local][q]
    } u;
    __shared__ float lred[8][64];

    const int bid = blockIdx.x;
    const int xcd = bid & 7, slot = bid >> 3;   // slot 0..63
    const int h = xcd * 2 + (slot & 1);
    const int qb = slot >> 1;                   // 0..31
    const int tid  = threadIdx.x;
    const int lane = tid & 63, w = tid >> 6;    // w in 0..7
    const int lo16 = lane & 15, quad = lane >> 4;

    bf16x8 qf[4][2];
    #pragma unroll
    for (int nq = 0; nq < 4; ++nq)
        #pragma unroll
        for (int dk = 0; dk < 2; ++dk)
            qf[nq][dk] = *(const bf16x8*)(qkv + (size_t)(qb * 64 + nq * 16 + lo16) * N_QKV
                                          + h * D_HEAD + dk * 32 + quad * 8);

    f32x4 o_t[4][4] = {};
    f32x4 o_l[4] = {};                          // l accumulated via MFMA ones-trick
    bf16x4 ones1;
    ones1[0] = (bf16)1.0f; ones1[1] = (bf16)1.0f; ones1[2] = (bf16)1.0f; ones1[3] = (bf16)1.0f;

    const bf16* kfb = qkv + (size_t)(w * 16 + lo16) * N_QKV + C_DIM + h * D_HEAD + quad * 8;
    const unsigned short* vb16 = (const unsigned short*)(qkv + 2 * C_DIM + h * D_HEAD);

    bf16x8 kf0 = *(const bf16x8*)(kfb);
    bf16x8 kf1 = *(const bf16x8*)(kfb + 32);
    unsigned short vreg[16];
    #pragma unroll
    for (int i = 0; i < 16; ++i)
        vreg[i] = vb16[(size_t)(w * 16 + i) * N_QKV + lane];

    bf16* vdst = &u.Vt[w >> 1][lane][(w & 1) * 16];

    for (int kt = 0; kt < T_DIM / 128; ++kt) {
        union { bf16x8 v; unsigned short us[8]; } p0, p1;
        #pragma unroll
        for (int i = 0; i < 8; ++i) { p0.us[i] = vreg[i]; p1.us[i] = vreg[8 + i]; }
        *(bf16x8*)vdst       = p0.v;
        *(bf16x8*)(vdst + 8) = p1.v;

        // early V-fragment reads: in-order DS makes these RAW-safe; their latency
        // hides under the prefetch issue + QK MFMA + exp2 below.
        bf16x4 vf[4];
        #pragma unroll
        for (int mi = 0; mi < 4; ++mi)
            vf[mi] = *(const bf16x4*)&u.Vt[w >> 1][mi * 16 + lo16][(w & 1) * 16 + quad * 4];

        bf16x8 nkf0 = kf0, nkf1 = kf1;
        if (kt + 1 < T_DIM / 128) {
            const bf16* kp = kfb + (size_t)(kt + 1) * 128 * N_QKV;
            nkf0 = *(const bf16x8*)(kp);
            nkf1 = *(const bf16x8*)(kp + 32);
            #pragma unroll
            for (int i = 0; i < 16; ++i)
                vreg[i] = vb16[(size_t)((kt + 1) * 128 + w * 16 + i) * N_QKV + lane];
        }

        f32x4 st[4];
        #pragma unroll
        for (int nq = 0; nq < 4; ++nq) {
            f32x4 z = {};
            z = __builtin_amdgcn_mfma_f32_16x16x32_bf16(kf0, qf[nq][0], z, 0, 0, 0);
            st[nq] = __builtin_amdgcn_mfma_f32_16x16x32_bf16(kf1, qf[nq][1], z, 0, 0, 0);
        }

        bf16x4 pb[4];
        #pragma unroll
        for (int nq = 0; nq < 4; ++nq)
            #pragma unroll
            for (int r = 0; r < 4; ++r)
                pb[nq][r] = (bf16)__builtin_amdgcn_exp2f(st[nq][r]);

        __builtin_amdgcn_s_setprio(1);
        #pragma unroll
        for (int nq = 0; nq < 4; ++nq)
            o_l[nq] = mfma16(ones1, pb[nq], o_l[nq]);
        #pragma unroll
        for (int mi = 0; mi < 4; ++mi)
            #pragma unroll
            for (int nq = 0; nq < 4; ++nq)
                o_t[mi][nq] = mfma16(vf[mi], pb[nq], o_t[mi][nq]);
        __builtin_amdgcn_s_setprio(0);

        kf0 = nkf0; kf1 = nkf1;
    }

    // o_l[nq][r] holds sum over this wave's 16 keys for q = nq*16+lo16
    #pragma unroll
    for (int nq = 0; nq < 4; ++nq)
        if (quad == 0) lred[w][nq * 16 + lo16] = o_l[nq][0];

    const int q8 = tid >> 3, dh = tid & 7;
    float linv = 0.f;
    #pragma unroll
    for (int mi = 0; mi < 4; ++mi) {
        __syncthreads();
        #pragma unroll
        for (int nq = 0; nq < 4; ++nq)
            #pragma unroll
            for (int r = 0; r < 4; ++r)
                u.Ored[w][quad * 4 + r][nq * 16 + lo16] = o_t[mi][nq][r];
        __syncthreads();
        if (mi == 0) {
            float ls = 0.f;
            #pragma unroll
            for (int j = 0; j < 8; ++j) ls += lred[j][q8];
            linv = 1.0f / ls;
        }
        bf16x2 ov;
        #pragma unroll
        for (int dj = 0; dj < 2; ++dj) {
            int d = dh * 2 + dj;
            float s = 0.f;
            #pragma unroll
            for (int j = 0; j < 8; ++j) s += u.Ored[j][d][q8];
            ov[dj] = (bf16)(s * linv);
        }
        *(bf16x2*)&y[(size_t)(qb * 64 + q8) * C_DIM + h * D_HEAD + mi * 16 + dh * 2] = ov;
    }
}

// ---------------- proj GEMM 64x64, BK=64, 2-phase DMA pipeline ----------------
#define PROJ_STAGE(BUF, K0) do {                                             \
    lds_load16(ga + (K0),      &As[BUF][0][(w * 16) * 32]);                  \
    lds_load16(ga + (K0) + 32, &As[BUF][1][(w * 16) * 32]);                  \
    lds_load16(gb + (K0),      &Bs[BUF][0][(w * 16) * 32]);                  \
    lds_load16(gb + (K0) + 32, &Bs[BUF][1][(w * 16) * 32]);                  \
} while (0)

#define PROJ_COMPUTE(BUF) do {                                               \
    _Pragma("unroll")                                                        \
    for (int p = 0; p < 2; ++p) {                                            \
        bf16x8 af[2], bfr[2];                                                \
        _Pragma("unroll")                                                    \
        for (int mi = 0; mi < 2; ++mi) af[mi]  = *(const bf16x8*)&As[BUF][p][(wm + mi * 16 + lo16) * 32 + quad * 8]; \
        _Pragma("unroll")                                                    \
        for (int ni = 0; ni < 2; ++ni) bfr[ni] = *(const bf16x8*)&Bs[BUF][p][(wn + ni * 16 + lo16) * 32 + quad * 8]; \
        _Pragma("unroll")                                                    \
        for (int mi = 0; mi < 2; ++mi)                                       \
            _Pragma("unroll")                                                \
            for (int ni = 0; ni < 2; ++ni)                                   \
                acc[mi][ni] = __builtin_amdgcn_mfma_f32_16x16x32_bf16(af[mi], bfr[ni], acc[mi][ni], 0, 0, 0); \
    }                                                                        \
} while (0)

__global__ __launch_bounds__(256, 4) void proj_gemm_kernel(
    const bf16* __restrict__ A, const bf16* __restrict__ Bt,
    const float* __restrict__ bias, float* __restrict__ out)
{
    __shared__ __align__(16) bf16 As[2][2][64 * 32];
    __shared__ __align__(16) bf16 Bs[2][2][64 * 32];
    const int bid = blockIdx.x;
    const int xcd = bid & 7, slot = bid >> 3;            // slot 0..63
    const int colBase = (xcd * 2 + (slot & 1)) * 64;
    const int rowBase = (slot >> 1) * 64;
    const int tid = threadIdx.x, lane = tid & 63, w = tid >> 6;
    const int lo16 = lane & 15, quad = lane >> 4;
    const int wm = (w & 1) * 32, wn = (w >> 1) * 32;

    const bf16* ga = A  + (size_t)(rowBase + w * 16 + (lane >> 2)) * C_DIM + (lane & 3) * 8;
    const bf16* gb = Bt + (size_t)(colBase + w * 16 + (lane >> 2)) * C_DIM + (lane & 3) * 8;

    f32x4 acc[2][2] = {};

    PROJ_STAGE(0, 0);
    WAIT_AND_BARRIER();

    for (int k0 = 0; k0 < C_DIM; k0 += 128) {
        PROJ_STAGE(1, k0 + 64);
        PROJ_COMPUTE(0);
        WAIT_AND_BARRIER();
        if (k0 + 128 < C_DIM) PROJ_STAGE(0, k0 + 128);
        PROJ_COMPUTE(1);
        WAIT_AND_BARRIER();
    }

    #pragma unroll
    for (int ni = 0; ni < 2; ++ni) {
        int col = colBase + wn + ni * 16 + lo16;
        float bv = bias[col];
        #pragma unroll
        for (int mi = 0; mi < 2; ++mi) {
            int row0 = rowBase + wm + mi * 16 + quad * 4;
            #pragma unroll
            for (int r = 0; r < 4; ++r)
                out[(size_t)(row0 + r) * C_DIM + col] = acc[mi][ni][r] + bv;
        }
    }
}

extern "C" void kernel_launch(void* const* d_in, const int* in_sizes, int n_in,
                              void* d_out, int out_size, void* d_ws, size_t ws_size,
                              hipStream_t stream) {
    const float* x      = (const float*)d_in[0];
    const float* W_qkv  = (const float*)d_in[1];
    const float* b_qkv  = (const float*)d_in[2];
    const float* W_proj = (const float*)d_in[3];
    const float* b_proj = (const float*)d_in[4];
    float* out = (float*)d_out;

    char* ws = (char*)d_ws;
    bf16* xb      = (bf16*)(ws);                 // [0,4) MB
    bf16* Wqkv_t  = (bf16*)(ws + (4  << 20));    // [4,10) MB
    bf16* Wproj_t = (bf16*)(ws + (10 << 20));    // [10,12) MB
    bf16* qkv_bf  = (bf16*)(ws + (12 << 20));    // [12,24) MB  interleaved [T][3072], Q prescaled
    bf16* yb      = (bf16*)(ws + (24 << 20));    // [24,28) MB

    prep_kernel<<<4096, 256, 0, stream>>>(x, xb, W_qkv, Wqkv_t);

    qkv_gemm_kernel<<<768, 256, 0, stream>>>(xb, Wqkv_t, b_qkv, qkv_bf, W_proj, Wproj_t);

    flash_kernel<<<512, 512, 0, stream>>>(qkv_bf, yb);

    proj_gemm_kernel<<<512, 256, 0, stream>>>(yb, Wproj_t, b_proj, out);
}